// Round 15
// baseline (133.158 us; speedup 1.0000x reference)
//
#include <hip/hip_runtime.h>

#define N 8192
#define KD 128
#define NCLS 10

typedef __attribute__((ext_vector_type(4))) int intx4;

// i8 fragment layout (K=64 per MFMA, two ks halves per K=128 row):
//   byte addr = idx16*2048 + ks*1024 + quad*256 + l16*16 + j   (k = ks*64+quad*16+j)
// Q holds rn(30*F) as i8; logit = (qa . qb) / 90.

// ---------------- k_conv: class sums FIRST (blocks 0..63), then i8 convert ----------
__global__ __launch_bounds__(256) void k_conv(const float* __restrict__ F,
                                              const int* __restrict__ tgt,
                                              float* __restrict__ diag10,
                                              int* __restrict__ Q,     // i8 frags of 30*F
                                              float* __restrict__ S,
                                              int* __restrict__ cnt,
                                              float* __restrict__ PS,
                                              int* __restrict__ Gi) {  // global min diag (int bits)
    int t = threadIdx.x;
    if (blockIdx.x < 64) {
        int b = blockIdx.x;                // 0..63
        int row0 = b * 128;
        int k = t & 127, h = t >> 7;
        __shared__ int lh[NCLS];
        if (t < NCLS) lh[t] = 0;
        __syncthreads();
        if (t < 128) atomicAdd(&lh[tgt[row0 + t]], 1);
        float local[NCLS];
#pragma unroll
        for (int c = 0; c < NCLS; ++c) local[c] = 0.f;
        for (int ii = 0; ii < 64; ++ii) {
            int row = row0 + h * 64 + ii;
            float v = F[(size_t)row * KD + k];
            int c = tgt[row];
#pragma unroll
            for (int cc = 0; cc < NCLS; ++cc) local[cc] += (cc == c) ? v : 0.f;
        }
        __shared__ float red[2][NCLS][KD];   // 10 KiB
#pragma unroll
        for (int cc = 0; cc < NCLS; ++cc) red[h][cc][k] = local[cc];
        __syncthreads();
        if (h == 0) {
#pragma unroll
            for (int cc = 0; cc < NCLS; ++cc)
                atomicAdd(&S[cc * KD + k], red[0][cc][k] + red[1][cc][k]);
            if (t < NCLS) atomicAdd(&cnt[t], lh[t]);
        }
    } else {
        int row0 = (blockIdx.x - 64) * 16;
        if (t < 16) PS[row0 + t] = 0.f;
        int col4 = t & 31;   // which float4 of the row (k = col4*4)
        int rg = t >> 5;     // 0..7
#pragma unroll
        for (int sw = 0; sw < 2; ++sw) {
            int row = row0 + sw * 8 + rg;
            float4 v = *(const float4*)(F + (size_t)row * KD + col4 * 4);
            float sq = v.x * v.x + v.y * v.y + v.z * v.z + v.w * v.w;
#pragma unroll
            for (int off = 16; off >= 1; off >>= 1) sq += __shfl_xor(sq, off);
            if (col4 == 0) {
                float dg = 10.f * sq;
                diag10[row] = dg;
                atomicMin(Gi, __float_as_int(dg));   // dg > 0: int-bit order == float order
            }
            // i8 quantize: q = rn(30*clamp(v, +-4.2))
            int q0 = __float2int_rn(30.f * fminf(fmaxf(v.x, -4.2f), 4.2f));
            int q1 = __float2int_rn(30.f * fminf(fmaxf(v.y, -4.2f), 4.2f));
            int q2 = __float2int_rn(30.f * fminf(fmaxf(v.z, -4.2f), 4.2f));
            int q3 = __float2int_rn(30.f * fminf(fmaxf(v.w, -4.2f), 4.2f));
            int dq = (q0 & 255) | ((q1 & 255) << 8) | ((q2 & 255) << 16) | ((q3 & 255) << 24);
            int idx = (row >> 4) * 512 + (col4 >> 4) * 256 + ((col4 >> 2) & 3) * 64 +
                      (row & 15) * 4 + (col4 & 3);
            Q[idx] = dq;
        }
    }
}

// ---------------- k_pair: symmetric-half i8 MFMA sweep, pipelined -------------------
// Grid (128, 4) = 512 blocks. Wave tile 64x64; wave handles col-slab offsets
// dd = y*16 + s*4 + w for s=0..3 (dd in 0..63), plus dd=64 for bx<64 (w==0,y==0).
// Each unordered slab pair is processed exactly once; off-diag cold fires add
// exp mass to BOTH row and col sides.
__global__ __launch_bounds__(256, 2) void k_pair(const unsigned char* __restrict__ Qb,
                                                 const float* __restrict__ diag10,
                                                 float* __restrict__ PS,
                                                 const int* __restrict__ Gi) {
    int bx = blockIdx.x, y = blockIdx.y;
    int tid = threadIdx.x;
    int w = tid >> 6, lane = tid & 63;
    int quad = lane >> 4, l16 = lane & 15;
    int row0 = bx * 64;

    int thrq = (int)((__int_as_float(*Gi) - 60.f) * 90.f);   // global, conservative

    // A fragments: coalesced 1024 B loads; af[it][ks] for rows row0 + it*16 + l16
    intx4 af[4][2];
#pragma unroll
    for (int it = 0; it < 4; ++it)
#pragma unroll
        for (int ks = 0; ks < 2; ++ks)
            af[it][ks] = *(const intx4*)(Qb + (size_t)(bx * 4 + it) * 2048 + ks * 1024 + lane * 16);

    bool ext = (y == 0) && (bx < 64) && (w == 0);   // handles the dd=64 tile

    // double-buffered B fragments
    intx4 bufs[2][4][2];
    {   // prologue: load step 0 (dd = y*16 + w)
        int col0 = ((bx + y * 16 + w) & 127) * 64;
        const unsigned char* bp = Qb + (size_t)(col0 >> 4) * 2048 + lane * 16;
#pragma unroll
        for (int tj = 0; tj < 4; ++tj)
#pragma unroll
            for (int ks = 0; ks < 2; ++ks)
                bufs[0][tj][ks] = *(const intx4*)(bp + tj * 2048 + ks * 1024);
    }

#pragma unroll
    for (int s = 0; s < 4; ++s) {
        // prefetch next tile (step s+1, or the dd=64 extra tile on the last step)
        if (s < 3) {
            int coln = ((bx + y * 16 + (s + 1) * 4 + w) & 127) * 64;
            const unsigned char* bp = Qb + (size_t)(coln >> 4) * 2048 + lane * 16;
#pragma unroll
            for (int tj = 0; tj < 4; ++tj)
#pragma unroll
                for (int ks = 0; ks < 2; ++ks)
                    bufs[(s + 1) & 1][tj][ks] = *(const intx4*)(bp + tj * 2048 + ks * 1024);
        } else if (ext) {
            int coln = (bx + 64) * 64;
            const unsigned char* bp = Qb + (size_t)(coln >> 4) * 2048 + lane * 16;
#pragma unroll
            for (int tj = 0; tj < 4; ++tj)
#pragma unroll
                for (int ks = 0; ks < 2; ++ks)
                    bufs[0][tj][ks] = *(const intx4*)(bp + tj * 2048 + ks * 1024);
        }

        int col0 = ((bx + y * 16 + s * 4 + w) & 127) * 64;

        intx4 acc[4][4];
#pragma unroll
        for (int it = 0; it < 4; ++it)
#pragma unroll
            for (int tj = 0; tj < 4; ++tj)
                acc[it][tj] = (intx4){0, 0, 0, 0};
#pragma unroll
        for (int ks = 0; ks < 2; ++ks)
#pragma unroll
            for (int it = 0; it < 4; ++it)
#pragma unroll
                for (int tj = 0; tj < 4; ++tj)
                    acc[it][tj] = __builtin_amdgcn_mfma_i32_16x16x64_i8(
                        af[it][ks], bufs[s & 1][tj][ks], acc[it][tj], 0, 0, 0);

        int mx = -2147483647;
#pragma unroll
        for (int it = 0; it < 4; ++it)
#pragma unroll
            for (int tj = 0; tj < 4; ++tj) {
                int a01 = max(acc[it][tj][0], acc[it][tj][1]);
                int a23 = max(acc[it][tj][2], acc[it][tj][3]);
                mx = max(mx, max(a01, a23));
            }

        if (__any(mx > thrq)) {
            bool has_diag = (col0 == row0);   // wave-uniform (dd==0)
            // row side: exp(l - M_row) into PS[row] (self excluded on diag tile)
#pragma unroll
            for (int it = 0; it < 4; ++it)
#pragma unroll
                for (int r = 0; r < 4; ++r) {
                    int grow = row0 + it * 16 + quad * 4 + r;
                    float Mrow = diag10[grow];
                    float rs = 0.f;
#pragma unroll
                    for (int tj = 0; tj < 4; ++tj) {
                        int gcol = col0 + tj * 16 + l16;
                        float lv = (float)acc[it][tj][r] * (1.f / 90.f);
                        float ev = __expf(lv - Mrow);
                        rs += (grow == gcol) ? 0.f : ev;
                    }
                    rs += __shfl_xor(rs, 1, 16);
                    rs += __shfl_xor(rs, 2, 16);
                    rs += __shfl_xor(rs, 4, 16);
                    rs += __shfl_xor(rs, 8, 16);
                    if (l16 == 0) atomicAdd(&PS[grow], rs);
                }
            // col side (off-diag tiles only): exp(l - M_col) into PS[col]
            if (!has_diag) {
#pragma unroll
                for (int tj = 0; tj < 4; ++tj) {
                    int gcol = col0 + tj * 16 + l16;
                    float Mcol = diag10[gcol];
                    float cs_ = 0.f;
#pragma unroll
                    for (int it = 0; it < 4; ++it)
#pragma unroll
                        for (int r = 0; r < 4; ++r)
                            cs_ += __expf((float)acc[it][tj][r] * (1.f / 90.f) - Mcol);
                    cs_ += __shfl_xor(cs_, 16);
                    cs_ += __shfl_xor(cs_, 32);
                    if (quad == 0) atomicAdd(&PS[gcol], cs_);
                }
            }
        }
    }

    // dd=64 extra tile (unordered pair {bx, bx+64}), off-diag semantics
    if (ext) {
        int col0 = (bx + 64) * 64;
        intx4 acc[4][4];
#pragma unroll
        for (int it = 0; it < 4; ++it)
#pragma unroll
            for (int tj = 0; tj < 4; ++tj)
                acc[it][tj] = (intx4){0, 0, 0, 0};
#pragma unroll
        for (int ks = 0; ks < 2; ++ks)
#pragma unroll
            for (int it = 0; it < 4; ++it)
#pragma unroll
                for (int tj = 0; tj < 4; ++tj)
                    acc[it][tj] = __builtin_amdgcn_mfma_i32_16x16x64_i8(
                        af[it][ks], bufs[0][tj][ks], acc[it][tj], 0, 0, 0);

        int mx = -2147483647;
#pragma unroll
        for (int it = 0; it < 4; ++it)
#pragma unroll
            for (int tj = 0; tj < 4; ++tj) {
                int a01 = max(acc[it][tj][0], acc[it][tj][1]);
                int a23 = max(acc[it][tj][2], acc[it][tj][3]);
                mx = max(mx, max(a01, a23));
            }
        if (__any(mx > thrq)) {
#pragma unroll
            for (int it = 0; it < 4; ++it)
#pragma unroll
                for (int r = 0; r < 4; ++r) {
                    int grow = row0 + it * 16 + quad * 4 + r;
                    float Mrow = diag10[grow];
                    float rs = 0.f;
#pragma unroll
                    for (int tj = 0; tj < 4; ++tj) {
                        float lv = (float)acc[it][tj][r] * (1.f / 90.f);
                        rs += __expf(lv - Mrow);
                    }
                    rs += __shfl_xor(rs, 1, 16);
                    rs += __shfl_xor(rs, 2, 16);
                    rs += __shfl_xor(rs, 4, 16);
                    rs += __shfl_xor(rs, 8, 16);
                    if (l16 == 0) atomicAdd(&PS[grow], rs);
                }
#pragma unroll
            for (int tj = 0; tj < 4; ++tj) {
                int gcol = col0 + tj * 16 + l16;
                float Mcol = diag10[gcol];
                float cs_ = 0.f;
#pragma unroll
                for (int it = 0; it < 4; ++it)
#pragma unroll
                    for (int r = 0; r < 4; ++r)
                        cs_ += __expf((float)acc[it][tj][r] * (1.f / 90.f) - Mcol);
                cs_ += __shfl_xor(cs_, 16);
                cs_ += __shfl_xor(cs_, 32);
                if (quad == 0) atomicAdd(&PS[gcol], cs_);
            }
        }
    }
}

// ---------------- k_final: posdot via S, log-term, reduce, ticket finalize -------
__global__ __launch_bounds__(256) void k_final(const float* __restrict__ F,
                                               const int* __restrict__ tgt,
                                               const float* __restrict__ diag10,
                                               const float* __restrict__ PS,
                                               const float* __restrict__ S,
                                               int* __restrict__ cnt,
                                               float* __restrict__ acc,
                                               float* __restrict__ out) {
    __shared__ float Ss[NCLS * KD];
    __shared__ int cs[NCLS];
    int t = threadIdx.x;
    for (int i = t; i < NCLS * KD; i += 256) Ss[i] = S[i];
    if (t < NCLS) cs[t] = cnt[t];
    __syncthreads();

    int g = t >> 2, q = t & 3;            // 4 lanes per row
    int row = blockIdx.x * 64 + g;
    int c = tgt[row];
    float dot = 0.f;
#pragma unroll
    for (int i = 0; i < 8; ++i) {
        float4 f = *(const float4*)(F + (size_t)row * KD + i * 16 + q * 4);
        float4 s = *(const float4*)(Ss + c * KD + i * 16 + q * 4);
        dot += f.x * s.x + f.y * s.y + f.z * s.z + f.w * s.w;
    }
    dot += __shfl_xor(dot, 1, 4);
    dot += __shfl_xor(dot, 2, 4);

    float mlp = 0.f;
    if (q == 0) {
        float M = diag10[row];
        float pp = 10.f * dot - M;            // sum over positives of logits
        float T = PS[row];                    // surviving shifted exp mass
        float np = (float)(cs[c] - 1);
        mlp = (np < 0.5f) ? 0.f : (pp - np * (M + __logf(T + 1e-20f))) / np;
    }
#pragma unroll
    for (int off = 32; off >= 1; off >>= 1) mlp += __shfl_xor(mlp, off);
    __shared__ float wsum[4];
    int lane = t & 63, w = t >> 6;
    if (lane == 0) wsum[w] = mlp;
    __syncthreads();
    if (t == 0) {
        atomicAdd(acc, (wsum[0] + wsum[1]) + (wsum[2] + wsum[3]));
        __threadfence();
        int old = atomicAdd(&cnt[12], 1);   // ticket
        if (old == (int)gridDim.x - 1) {
            float tot = atomicAdd(acc, 0.0f);   // coherent read of total
            double sp = 0.0, sn = 0.0;
            for (int cc = 0; cc < NCLS; ++cc) {
                double n = (double)cs[cc];
                sp += n * (n - 1.0);
                sn += n * ((double)N - n);
            }
            out[0] = (float)(-(0.1 / 0.07) * ((double)tot / (double)N));
            out[1] = (float)(sp / (double)N);
            out[2] = (float)(sn / (double)N);
        }
    }
}

extern "C" void kernel_launch(void* const* d_in, const int* in_sizes, int n_in,
                              void* d_out, int out_size, void* d_ws, size_t ws_size,
                              hipStream_t stream) {
    const float* F = (const float*)d_in[0];
    const int* tgt = (const int*)d_in[1];
    float* out = (float*)d_out;
    char* ws = (char*)d_ws;

    int* cnt = (int*)(ws);                       // 64 B (ticket at cnt[12])
    float* acc = (float*)(ws + 64);              // 4 B
    float* S = (float*)(ws + 128);               // 5120 B -> ends 5248
    float* PS = (float*)(ws + 8192);             // 32 KiB (zeroed by k_conv)
    int* Gi = (int*)(ws + 49152);                // 4 B (init 0x7F7F7F7F ~ +3.4e38)
    float* diag10 = (float*)(ws + 65536);        // 32 KiB
    int* Q = (int*)(ws + (1u << 20));            // 1 MiB (i8 frags of 30*F)

    hipMemsetAsync(ws, 0, 8192, stream);         // cnt + acc + S
    hipMemsetAsync(ws + 49152, 0x7F, 4, stream); // Gi = huge positive float
    k_conv<<<576, 256, 0, stream>>>(F, tgt, diag10, Q, S, cnt, PS, Gi);
    k_pair<<<dim3(128, 4), 256, 0, stream>>>((const unsigned char*)Q, diag10, PS, Gi);
    k_final<<<N / 64, 256, 0, stream>>>(F, tgt, diag10, PS, S, cnt, acc, out);
}

// Round 16
// 88.061 us; speedup vs baseline: 1.5121x; 1.5121x over previous
//
#include <hip/hip_runtime.h>

#define N 8192
#define KD 128
#define NCLS 10

typedef __attribute__((ext_vector_type(4))) int intx4;

// i8 fragment layout (K=64 per MFMA, two ks halves per K=128 row):
//   byte addr = idx16*2048 + ks*1024 + quad*256 + l16*16 + j   (k = ks*64+quad*16+j)
// Q holds rn(30*F) as i8; logit = (qa . qb) / 90.

// ---------------- k_conv: class sums FIRST (blocks 0..63), then i8 convert ----------
// Dmin[128]: per-64-row-slab min of diag10, via one spread atomicMin per conv block.
__global__ __launch_bounds__(256) void k_conv(const float* __restrict__ F,
                                              const int* __restrict__ tgt,
                                              float* __restrict__ diag10,
                                              int* __restrict__ Q,     // i8 frags of 30*F
                                              float* __restrict__ S,
                                              int* __restrict__ cnt,
                                              float* __restrict__ PS,
                                              int* __restrict__ Dmin) {
    int t = threadIdx.x;
    if (blockIdx.x < 64) {
        int b = blockIdx.x;                // 0..63
        int row0 = b * 128;
        int k = t & 127, h = t >> 7;
        __shared__ int lh[NCLS];
        if (t < NCLS) lh[t] = 0;
        __syncthreads();
        if (t < 128) atomicAdd(&lh[tgt[row0 + t]], 1);
        float local[NCLS];
#pragma unroll
        for (int c = 0; c < NCLS; ++c) local[c] = 0.f;
        for (int ii = 0; ii < 64; ++ii) {
            int row = row0 + h * 64 + ii;
            float v = F[(size_t)row * KD + k];
            int c = tgt[row];
#pragma unroll
            for (int cc = 0; cc < NCLS; ++cc) local[cc] += (cc == c) ? v : 0.f;
        }
        __shared__ float red[2][NCLS][KD];   // 10 KiB
#pragma unroll
        for (int cc = 0; cc < NCLS; ++cc) red[h][cc][k] = local[cc];
        __syncthreads();
        if (h == 0) {
#pragma unroll
            for (int cc = 0; cc < NCLS; ++cc)
                atomicAdd(&S[cc * KD + k], red[0][cc][k] + red[1][cc][k]);
            if (t < NCLS) atomicAdd(&cnt[t], lh[t]);
        }
    } else {
        int row0 = (blockIdx.x - 64) * 16;
        __shared__ int bmin;
        if (t == 0) bmin = 0x7f7fffff;       // +3.4e38 bits
        __syncthreads();
        if (t < 16) PS[row0 + t] = 0.f;
        int col4 = t & 31;   // which float4 of the row (k = col4*4)
        int rg = t >> 5;     // 0..7
#pragma unroll
        for (int sw = 0; sw < 2; ++sw) {
            int row = row0 + sw * 8 + rg;
            float4 v = *(const float4*)(F + (size_t)row * KD + col4 * 4);
            float sq = v.x * v.x + v.y * v.y + v.z * v.z + v.w * v.w;
#pragma unroll
            for (int off = 16; off >= 1; off >>= 1) sq += __shfl_xor(sq, off);
            if (col4 == 0) {
                float dg = 10.f * sq;
                diag10[row] = dg;
                atomicMin(&bmin, __float_as_int(dg));   // LDS atomic, 16/block
            }
            // i8 quantize: q = rn(30*clamp(v, +-4.2))
            int q0 = __float2int_rn(30.f * fminf(fmaxf(v.x, -4.2f), 4.2f));
            int q1 = __float2int_rn(30.f * fminf(fmaxf(v.y, -4.2f), 4.2f));
            int q2 = __float2int_rn(30.f * fminf(fmaxf(v.z, -4.2f), 4.2f));
            int q3 = __float2int_rn(30.f * fminf(fmaxf(v.w, -4.2f), 4.2f));
            int dq = (q0 & 255) | ((q1 & 255) << 8) | ((q2 & 255) << 16) | ((q3 & 255) << 24);
            int idx = (row >> 4) * 512 + (col4 >> 4) * 256 + ((col4 >> 2) & 3) * 64 +
                      (row & 15) * 4 + (col4 & 3);
            Q[idx] = dq;
        }
        __syncthreads();
        if (t == 0) atomicMin(&Dmin[(blockIdx.x - 64) >> 2], bmin);  // 4 per address
    }
}

// ---------------- k_pair: symmetric-half i8 MFMA sweep, pipelined -------------------
// Grid (128, 4) = 512 blocks. Wave tile 64x64; wave handles col-slab offsets
// dd = y*16 + s*4 + w for s=0..3 (dd in 0..63), plus dd=64 for bx<64 (w==0,y==0).
// Each unordered slab pair is processed exactly once; off-diag cold fires add
// exp mass to BOTH row and col sides.
__global__ __launch_bounds__(256, 2) void k_pair(const unsigned char* __restrict__ Qb,
                                                 const float* __restrict__ diag10,
                                                 float* __restrict__ PS,
                                                 const int* __restrict__ Dmin) {
    int bx = blockIdx.x, y = blockIdx.y;
    int tid = threadIdx.x;
    int w = tid >> 6, lane = tid & 63;
    int quad = lane >> 4, l16 = lane & 15;
    int row0 = bx * 64;

    float dmr = __int_as_float(Dmin[bx]);   // row-slab min diag

    // A fragments: coalesced 1024 B loads; af[it][ks] for rows row0 + it*16 + l16
    intx4 af[4][2];
#pragma unroll
    for (int it = 0; it < 4; ++it)
#pragma unroll
        for (int ks = 0; ks < 2; ++ks)
            af[it][ks] = *(const intx4*)(Qb + (size_t)(bx * 4 + it) * 2048 + ks * 1024 + lane * 16);

    bool ext = (y == 0) && (bx < 64) && (w == 0);   // handles the dd=64 tile

    // double-buffered B fragments
    intx4 bufs[2][4][2];
    {   // prologue: load step 0 (dd = y*16 + w)
        int col0 = ((bx + y * 16 + w) & 127) * 64;
        const unsigned char* bp = Qb + (size_t)(col0 >> 4) * 2048 + lane * 16;
#pragma unroll
        for (int tj = 0; tj < 4; ++tj)
#pragma unroll
            for (int ks = 0; ks < 2; ++ks)
                bufs[0][tj][ks] = *(const intx4*)(bp + tj * 2048 + ks * 1024);
    }

#pragma unroll
    for (int s = 0; s < 4; ++s) {
        // prefetch next tile (step s+1, or the dd=64 extra tile on the last step)
        if (s < 3) {
            int coln = ((bx + y * 16 + (s + 1) * 4 + w) & 127) * 64;
            const unsigned char* bp = Qb + (size_t)(coln >> 4) * 2048 + lane * 16;
#pragma unroll
            for (int tj = 0; tj < 4; ++tj)
#pragma unroll
                for (int ks = 0; ks < 2; ++ks)
                    bufs[(s + 1) & 1][tj][ks] = *(const intx4*)(bp + tj * 2048 + ks * 1024);
        } else if (ext) {
            int coln = (bx + 64) * 64;
            const unsigned char* bp = Qb + (size_t)(coln >> 4) * 2048 + lane * 16;
#pragma unroll
            for (int tj = 0; tj < 4; ++tj)
#pragma unroll
                for (int ks = 0; ks < 2; ++ks)
                    bufs[0][tj][ks] = *(const intx4*)(bp + tj * 2048 + ks * 1024);
        }

        int csb = (bx + y * 16 + s * 4 + w) & 127;   // col slab index
        int col0 = csb * 64;
        int thrq = (int)((fminf(dmr, __int_as_float(Dmin[csb])) - 60.f) * 90.f);

        intx4 acc[4][4];
#pragma unroll
        for (int it = 0; it < 4; ++it)
#pragma unroll
            for (int tj = 0; tj < 4; ++tj)
                acc[it][tj] = (intx4){0, 0, 0, 0};
#pragma unroll
        for (int ks = 0; ks < 2; ++ks)
#pragma unroll
            for (int it = 0; it < 4; ++it)
#pragma unroll
                for (int tj = 0; tj < 4; ++tj)
                    acc[it][tj] = __builtin_amdgcn_mfma_i32_16x16x64_i8(
                        af[it][ks], bufs[s & 1][tj][ks], acc[it][tj], 0, 0, 0);

        int mx = -2147483647;
#pragma unroll
        for (int it = 0; it < 4; ++it)
#pragma unroll
            for (int tj = 0; tj < 4; ++tj) {
                int a01 = max(acc[it][tj][0], acc[it][tj][1]);
                int a23 = max(acc[it][tj][2], acc[it][tj][3]);
                mx = max(mx, max(a01, a23));
            }

        if (__any(mx > thrq)) {
            bool has_diag = (col0 == row0);   // wave-uniform (dd==0)
            // row side: exp(l - M_row) into PS[row] (self excluded on diag tile)
#pragma unroll
            for (int it = 0; it < 4; ++it)
#pragma unroll
                for (int r = 0; r < 4; ++r) {
                    int grow = row0 + it * 16 + quad * 4 + r;
                    float Mrow = diag10[grow];
                    float rs = 0.f;
#pragma unroll
                    for (int tj = 0; tj < 4; ++tj) {
                        int gcol = col0 + tj * 16 + l16;
                        float lv = (float)acc[it][tj][r] * (1.f / 90.f);
                        float ev = __expf(lv - Mrow);
                        rs += (grow == gcol) ? 0.f : ev;
                    }
                    rs += __shfl_xor(rs, 1, 16);
                    rs += __shfl_xor(rs, 2, 16);
                    rs += __shfl_xor(rs, 4, 16);
                    rs += __shfl_xor(rs, 8, 16);
                    if (l16 == 0) atomicAdd(&PS[grow], rs);
                }
            // col side (off-diag tiles only): exp(l - M_col) into PS[col]
            if (!has_diag) {
#pragma unroll
                for (int tj = 0; tj < 4; ++tj) {
                    int gcol = col0 + tj * 16 + l16;
                    float Mcol = diag10[gcol];
                    float cs_ = 0.f;
#pragma unroll
                    for (int it = 0; it < 4; ++it)
#pragma unroll
                        for (int r = 0; r < 4; ++r)
                            cs_ += __expf((float)acc[it][tj][r] * (1.f / 90.f) - Mcol);
                    cs_ += __shfl_xor(cs_, 16);
                    cs_ += __shfl_xor(cs_, 32);
                    if (quad == 0) atomicAdd(&PS[gcol], cs_);
                }
            }
        }
    }

    // dd=64 extra tile (unordered pair {bx, bx+64}), off-diag semantics
    if (ext) {
        int col0 = (bx + 64) * 64;
        int thrq = (int)((fminf(dmr, __int_as_float(Dmin[bx + 64])) - 60.f) * 90.f);
        intx4 acc[4][4];
#pragma unroll
        for (int it = 0; it < 4; ++it)
#pragma unroll
            for (int tj = 0; tj < 4; ++tj)
                acc[it][tj] = (intx4){0, 0, 0, 0};
#pragma unroll
        for (int ks = 0; ks < 2; ++ks)
#pragma unroll
            for (int it = 0; it < 4; ++it)
#pragma unroll
                for (int tj = 0; tj < 4; ++tj)
                    acc[it][tj] = __builtin_amdgcn_mfma_i32_16x16x64_i8(
                        af[it][ks], bufs[0][tj][ks], acc[it][tj], 0, 0, 0);

        int mx = -2147483647;
#pragma unroll
        for (int it = 0; it < 4; ++it)
#pragma unroll
            for (int tj = 0; tj < 4; ++tj) {
                int a01 = max(acc[it][tj][0], acc[it][tj][1]);
                int a23 = max(acc[it][tj][2], acc[it][tj][3]);
                mx = max(mx, max(a01, a23));
            }
        if (__any(mx > thrq)) {
#pragma unroll
            for (int it = 0; it < 4; ++it)
#pragma unroll
                for (int r = 0; r < 4; ++r) {
                    int grow = row0 + it * 16 + quad * 4 + r;
                    float Mrow = diag10[grow];
                    float rs = 0.f;
#pragma unroll
                    for (int tj = 0; tj < 4; ++tj) {
                        float lv = (float)acc[it][tj][r] * (1.f / 90.f);
                        rs += __expf(lv - Mrow);
                    }
                    rs += __shfl_xor(rs, 1, 16);
                    rs += __shfl_xor(rs, 2, 16);
                    rs += __shfl_xor(rs, 4, 16);
                    rs += __shfl_xor(rs, 8, 16);
                    if (l16 == 0) atomicAdd(&PS[grow], rs);
                }
#pragma unroll
            for (int tj = 0; tj < 4; ++tj) {
                int gcol = col0 + tj * 16 + l16;
                float Mcol = diag10[gcol];
                float cs_ = 0.f;
#pragma unroll
                for (int it = 0; it < 4; ++it)
#pragma unroll
                    for (int r = 0; r < 4; ++r)
                        cs_ += __expf((float)acc[it][tj][r] * (1.f / 90.f) - Mcol);
                cs_ += __shfl_xor(cs_, 16);
                cs_ += __shfl_xor(cs_, 32);
                if (quad == 0) atomicAdd(&PS[gcol], cs_);
            }
        }
    }
}

// ---------------- k_final: posdot via S, log-term, reduce, ticket finalize -------
__global__ __launch_bounds__(256) void k_final(const float* __restrict__ F,
                                               const int* __restrict__ tgt,
                                               const float* __restrict__ diag10,
                                               const float* __restrict__ PS,
                                               const float* __restrict__ S,
                                               int* __restrict__ cnt,
                                               float* __restrict__ acc,
                                               float* __restrict__ out) {
    __shared__ float Ss[NCLS * KD];
    __shared__ int cs[NCLS];
    int t = threadIdx.x;
    for (int i = t; i < NCLS * KD; i += 256) Ss[i] = S[i];
    if (t < NCLS) cs[t] = cnt[t];
    __syncthreads();

    int g = t >> 2, q = t & 3;            // 4 lanes per row
    int row = blockIdx.x * 64 + g;
    int c = tgt[row];
    float dot = 0.f;
#pragma unroll
    for (int i = 0; i < 8; ++i) {
        float4 f = *(const float4*)(F + (size_t)row * KD + i * 16 + q * 4);
        float4 s = *(const float4*)(Ss + c * KD + i * 16 + q * 4);
        dot += f.x * s.x + f.y * s.y + f.z * s.z + f.w * s.w;
    }
    dot += __shfl_xor(dot, 1, 4);
    dot += __shfl_xor(dot, 2, 4);

    float mlp = 0.f;
    if (q == 0) {
        float M = diag10[row];
        float pp = 10.f * dot - M;            // sum over positives of logits
        float T = PS[row];                    // surviving shifted exp mass
        float np = (float)(cs[c] - 1);
        mlp = (np < 0.5f) ? 0.f : (pp - np * (M + __logf(T + 1e-20f))) / np;
    }
#pragma unroll
    for (int off = 32; off >= 1; off >>= 1) mlp += __shfl_xor(mlp, off);
    __shared__ float wsum[4];
    int lane = t & 63, w = t >> 6;
    if (lane == 0) wsum[w] = mlp;
    __syncthreads();
    if (t == 0) {
        atomicAdd(acc, (wsum[0] + wsum[1]) + (wsum[2] + wsum[3]));
        __threadfence();
        int old = atomicAdd(&cnt[12], 1);   // ticket
        if (old == (int)gridDim.x - 1) {
            float tot = atomicAdd(acc, 0.0f);   // coherent read of total
            double sp = 0.0, sn = 0.0;
            for (int cc = 0; cc < NCLS; ++cc) {
                double n = (double)cs[cc];
                sp += n * (n - 1.0);
                sn += n * ((double)N - n);
            }
            out[0] = (float)(-(0.1 / 0.07) * ((double)tot / (double)N));
            out[1] = (float)(sp / (double)N);
            out[2] = (float)(sn / (double)N);
        }
    }
}

extern "C" void kernel_launch(void* const* d_in, const int* in_sizes, int n_in,
                              void* d_out, int out_size, void* d_ws, size_t ws_size,
                              hipStream_t stream) {
    const float* F = (const float*)d_in[0];
    const int* tgt = (const int*)d_in[1];
    float* out = (float*)d_out;
    char* ws = (char*)d_ws;

    int* cnt = (int*)(ws);                       // 64 B (ticket at cnt[12])
    float* acc = (float*)(ws + 64);              // 4 B
    float* S = (float*)(ws + 128);               // 5120 B -> ends 5248
    float* PS = (float*)(ws + 8192);             // 32 KiB (zeroed by k_conv)
    int* Dmin = (int*)(ws + 49152);              // 512 B (per-slab min diag bits)
    float* diag10 = (float*)(ws + 65536);        // 32 KiB
    int* Q = (int*)(ws + (1u << 20));            // 1 MiB (i8 frags of 30*F)

    hipMemsetAsync(ws, 0, 8192, stream);         // cnt + acc + S
    hipMemsetAsync(ws + 49152, 0x7F, 512, stream);   // Dmin = +3.4e38
    k_conv<<<576, 256, 0, stream>>>(F, tgt, diag10, Q, S, cnt, PS, Dmin);
    k_pair<<<dim3(128, 4), 256, 0, stream>>>((const unsigned char*)Q, diag10, PS, Dmin);
    k_final<<<N / 64, 256, 0, stream>>>(F, tgt, diag10, PS, S, cnt, acc, out);
}

// Round 17
// 83.680 us; speedup vs baseline: 1.5913x; 1.0523x over previous
//
#include <hip/hip_runtime.h>

#define N 8192
#define KD 128
#define NCLS 10

typedef __attribute__((ext_vector_type(4))) int intx4;

// i8 fragment layout (K=64 per MFMA, two ks halves per K=128 row):
//   byte addr = idx16*2048 + ks*1024 + quad*256 + l16*16 + j   (k = ks*64+quad*16+j)
// Q holds rn(30*F) as i8; logit = (qa . qb) / 90.

__device__ __forceinline__ float slabmin(const int* __restrict__ Dpart, int slab) {
    float a = fminf(__int_as_float(Dpart[slab * 4 + 0]), __int_as_float(Dpart[slab * 4 + 1]));
    float b = fminf(__int_as_float(Dpart[slab * 4 + 2]), __int_as_float(Dpart[slab * 4 + 3]));
    return fminf(a, b);
}

// ---------------- k_conv: class sums (blocks 0..127) | i8 convert (128..639) --------
// Convert blocks plain-store their 16-row diag-min into Dpart[bid] (no init, no atomics).
__global__ __launch_bounds__(256) void k_conv(const float* __restrict__ F,
                                              const int* __restrict__ tgt,
                                              float* __restrict__ diag10,
                                              int* __restrict__ Q,     // i8 frags of 30*F
                                              float* __restrict__ S,
                                              int* __restrict__ cnt,
                                              float* __restrict__ PS,
                                              int* __restrict__ Dpart) {
    int t = threadIdx.x;
    if (blockIdx.x < 128) {
        int row0 = blockIdx.x * 64;        // 64 rows per class-sum block
        int k = t & 127, h = t >> 7;
        __shared__ int lh[NCLS];
        if (t < NCLS) lh[t] = 0;
        __syncthreads();
        if (t < 64) atomicAdd(&lh[tgt[row0 + t]], 1);
        float local[NCLS];
#pragma unroll
        for (int c = 0; c < NCLS; ++c) local[c] = 0.f;
        for (int ii = 0; ii < 32; ++ii) {
            int row = row0 + h * 32 + ii;
            float v = F[(size_t)row * KD + k];
            int c = tgt[row];
#pragma unroll
            for (int cc = 0; cc < NCLS; ++cc) local[cc] += (cc == c) ? v : 0.f;
        }
        __shared__ float red[2][NCLS][KD];   // 10 KiB
#pragma unroll
        for (int cc = 0; cc < NCLS; ++cc) red[h][cc][k] = local[cc];
        __syncthreads();
        if (h == 0) {
#pragma unroll
            for (int cc = 0; cc < NCLS; ++cc)
                atomicAdd(&S[cc * KD + k], red[0][cc][k] + red[1][cc][k]);
            if (t < NCLS) atomicAdd(&cnt[t], lh[t]);
        }
    } else {
        int bid = blockIdx.x - 128;          // 0..511
        int row0 = bid * 16;
        __shared__ int bmin;
        if (t == 0) bmin = 0x7f7fffff;       // +3.4e38 bits
        __syncthreads();
        if (t < 16) PS[row0 + t] = 0.f;
        int col4 = t & 31;   // which float4 of the row (k = col4*4)
        int rg = t >> 5;     // 0..7
#pragma unroll
        for (int sw = 0; sw < 2; ++sw) {
            int row = row0 + sw * 8 + rg;
            float4 v = *(const float4*)(F + (size_t)row * KD + col4 * 4);
            float sq = v.x * v.x + v.y * v.y + v.z * v.z + v.w * v.w;
#pragma unroll
            for (int off = 16; off >= 1; off >>= 1) sq += __shfl_xor(sq, off);
            if (col4 == 0) {
                float dg = 10.f * sq;
                diag10[row] = dg;
                atomicMin(&bmin, __float_as_int(dg));   // LDS atomic, 16/block
            }
            // i8 quantize: q = rn(30*clamp(v, +-4.2))
            int q0 = __float2int_rn(30.f * fminf(fmaxf(v.x, -4.2f), 4.2f));
            int q1 = __float2int_rn(30.f * fminf(fmaxf(v.y, -4.2f), 4.2f));
            int q2 = __float2int_rn(30.f * fminf(fmaxf(v.z, -4.2f), 4.2f));
            int q3 = __float2int_rn(30.f * fminf(fmaxf(v.w, -4.2f), 4.2f));
            int dq = (q0 & 255) | ((q1 & 255) << 8) | ((q2 & 255) << 16) | ((q3 & 255) << 24);
            int idx = (row >> 4) * 512 + (col4 >> 4) * 256 + ((col4 >> 2) & 3) * 64 +
                      (row & 15) * 4 + (col4 & 3);
            Q[idx] = dq;
        }
        __syncthreads();
        if (t == 0) Dpart[bid] = bmin;       // plain store, no init required
    }
}

// ---------------- k_pair: symmetric-half i8 MFMA sweep, pipelined -------------------
// Grid (128, 4) = 512 blocks. Wave tile 64x64; wave handles col-slab offsets
// dd = y*16 + s*4 + w for s=0..3 (dd in 0..63), plus dd=64 for bx<64 (w==0,y==0).
// Each unordered slab pair is processed exactly once; off-diag cold fires add
// exp mass to BOTH row and col sides.
__global__ __launch_bounds__(256, 2) void k_pair(const unsigned char* __restrict__ Qb,
                                                 const float* __restrict__ diag10,
                                                 float* __restrict__ PS,
                                                 const int* __restrict__ Dpart) {
    int bx = blockIdx.x, y = blockIdx.y;
    int tid = threadIdx.x;
    int w = tid >> 6, lane = tid & 63;
    int quad = lane >> 4, l16 = lane & 15;
    int row0 = bx * 64;

    float dmr = slabmin(Dpart, bx);   // row-slab min diag

    // A fragments: coalesced 1024 B loads; af[it][ks] for rows row0 + it*16 + l16
    intx4 af[4][2];
#pragma unroll
    for (int it = 0; it < 4; ++it)
#pragma unroll
        for (int ks = 0; ks < 2; ++ks)
            af[it][ks] = *(const intx4*)(Qb + (size_t)(bx * 4 + it) * 2048 + ks * 1024 + lane * 16);

    bool ext = (y == 0) && (bx < 64) && (w == 0);   // handles the dd=64 tile

    // double-buffered B fragments
    intx4 bufs[2][4][2];
    {   // prologue: load step 0 (dd = y*16 + w)
        int col0 = ((bx + y * 16 + w) & 127) * 64;
        const unsigned char* bp = Qb + (size_t)(col0 >> 4) * 2048 + lane * 16;
#pragma unroll
        for (int tj = 0; tj < 4; ++tj)
#pragma unroll
            for (int ks = 0; ks < 2; ++ks)
                bufs[0][tj][ks] = *(const intx4*)(bp + tj * 2048 + ks * 1024);
    }

#pragma unroll
    for (int s = 0; s < 4; ++s) {
        // prefetch next tile (step s+1, or the dd=64 extra tile on the last step)
        if (s < 3) {
            int coln = ((bx + y * 16 + (s + 1) * 4 + w) & 127) * 64;
            const unsigned char* bp = Qb + (size_t)(coln >> 4) * 2048 + lane * 16;
#pragma unroll
            for (int tj = 0; tj < 4; ++tj)
#pragma unroll
                for (int ks = 0; ks < 2; ++ks)
                    bufs[(s + 1) & 1][tj][ks] = *(const intx4*)(bp + tj * 2048 + ks * 1024);
        } else if (ext) {
            int coln = (bx + 64) * 64;
            const unsigned char* bp = Qb + (size_t)(coln >> 4) * 2048 + lane * 16;
#pragma unroll
            for (int tj = 0; tj < 4; ++tj)
#pragma unroll
                for (int ks = 0; ks < 2; ++ks)
                    bufs[0][tj][ks] = *(const intx4*)(bp + tj * 2048 + ks * 1024);
        }

        int csb = (bx + y * 16 + s * 4 + w) & 127;   // col slab index
        int col0 = csb * 64;
        int thrq = (int)((fminf(dmr, slabmin(Dpart, csb)) - 60.f) * 90.f);

        intx4 acc[4][4];
#pragma unroll
        for (int it = 0; it < 4; ++it)
#pragma unroll
            for (int tj = 0; tj < 4; ++tj)
                acc[it][tj] = (intx4){0, 0, 0, 0};
#pragma unroll
        for (int ks = 0; ks < 2; ++ks)
#pragma unroll
            for (int it = 0; it < 4; ++it)
#pragma unroll
                for (int tj = 0; tj < 4; ++tj)
                    acc[it][tj] = __builtin_amdgcn_mfma_i32_16x16x64_i8(
                        af[it][ks], bufs[s & 1][tj][ks], acc[it][tj], 0, 0, 0);

        int mx = -2147483647;
#pragma unroll
        for (int it = 0; it < 4; ++it)
#pragma unroll
            for (int tj = 0; tj < 4; ++tj) {
                int a01 = max(acc[it][tj][0], acc[it][tj][1]);
                int a23 = max(acc[it][tj][2], acc[it][tj][3]);
                mx = max(mx, max(a01, a23));
            }

        if (__any(mx > thrq)) {
            bool has_diag = (col0 == row0);   // wave-uniform (dd==0)
            // row side: exp(l - M_row) into PS[row] (self excluded on diag tile)
#pragma unroll
            for (int it = 0; it < 4; ++it)
#pragma unroll
                for (int r = 0; r < 4; ++r) {
                    int grow = row0 + it * 16 + quad * 4 + r;
                    float Mrow = diag10[grow];
                    float rs = 0.f;
#pragma unroll
                    for (int tj = 0; tj < 4; ++tj) {
                        int gcol = col0 + tj * 16 + l16;
                        float lv = (float)acc[it][tj][r] * (1.f / 90.f);
                        float ev = __expf(lv - Mrow);
                        rs += (grow == gcol) ? 0.f : ev;
                    }
                    rs += __shfl_xor(rs, 1, 16);
                    rs += __shfl_xor(rs, 2, 16);
                    rs += __shfl_xor(rs, 4, 16);
                    rs += __shfl_xor(rs, 8, 16);
                    if (l16 == 0) atomicAdd(&PS[grow], rs);
                }
            // col side (off-diag tiles only): exp(l - M_col) into PS[col]
            if (!has_diag) {
#pragma unroll
                for (int tj = 0; tj < 4; ++tj) {
                    int gcol = col0 + tj * 16 + l16;
                    float Mcol = diag10[gcol];
                    float cs_ = 0.f;
#pragma unroll
                    for (int it = 0; it < 4; ++it)
#pragma unroll
                        for (int r = 0; r < 4; ++r)
                            cs_ += __expf((float)acc[it][tj][r] * (1.f / 90.f) - Mcol);
                    cs_ += __shfl_xor(cs_, 16);
                    cs_ += __shfl_xor(cs_, 32);
                    if (quad == 0) atomicAdd(&PS[gcol], cs_);
                }
            }
        }
    }

    // dd=64 extra tile (unordered pair {bx, bx+64}), off-diag semantics
    if (ext) {
        int col0 = (bx + 64) * 64;
        int thrq = (int)((fminf(dmr, slabmin(Dpart, bx + 64)) - 60.f) * 90.f);
        intx4 acc[4][4];
#pragma unroll
        for (int it = 0; it < 4; ++it)
#pragma unroll
            for (int tj = 0; tj < 4; ++tj)
                acc[it][tj] = (intx4){0, 0, 0, 0};
#pragma unroll
        for (int ks = 0; ks < 2; ++ks)
#pragma unroll
            for (int it = 0; it < 4; ++it)
#pragma unroll
                for (int tj = 0; tj < 4; ++tj)
                    acc[it][tj] = __builtin_amdgcn_mfma_i32_16x16x64_i8(
                        af[it][ks], bufs[0][tj][ks], acc[it][tj], 0, 0, 0);

        int mx = -2147483647;
#pragma unroll
        for (int it = 0; it < 4; ++it)
#pragma unroll
            for (int tj = 0; tj < 4; ++tj) {
                int a01 = max(acc[it][tj][0], acc[it][tj][1]);
                int a23 = max(acc[it][tj][2], acc[it][tj][3]);
                mx = max(mx, max(a01, a23));
            }
        if (__any(mx > thrq)) {
#pragma unroll
            for (int it = 0; it < 4; ++it)
#pragma unroll
                for (int r = 0; r < 4; ++r) {
                    int grow = row0 + it * 16 + quad * 4 + r;
                    float Mrow = diag10[grow];
                    float rs = 0.f;
#pragma unroll
                    for (int tj = 0; tj < 4; ++tj) {
                        float lv = (float)acc[it][tj][r] * (1.f / 90.f);
                        rs += __expf(lv - Mrow);
                    }
                    rs += __shfl_xor(rs, 1, 16);
                    rs += __shfl_xor(rs, 2, 16);
                    rs += __shfl_xor(rs, 4, 16);
                    rs += __shfl_xor(rs, 8, 16);
                    if (l16 == 0) atomicAdd(&PS[grow], rs);
                }
#pragma unroll
            for (int tj = 0; tj < 4; ++tj) {
                int gcol = col0 + tj * 16 + l16;
                float Mcol = diag10[gcol];
                float cs_ = 0.f;
#pragma unroll
                for (int it = 0; it < 4; ++it)
#pragma unroll
                    for (int r = 0; r < 4; ++r)
                        cs_ += __expf((float)acc[it][tj][r] * (1.f / 90.f) - Mcol);
                cs_ += __shfl_xor(cs_, 16);
                cs_ += __shfl_xor(cs_, 32);
                if (quad == 0) atomicAdd(&PS[gcol], cs_);
            }
        }
    }
}

// ---------------- k_final: posdot via S, log-term, reduce, ticket finalize -------
__global__ __launch_bounds__(256) void k_final(const float* __restrict__ F,
                                               const int* __restrict__ tgt,
                                               const float* __restrict__ diag10,
                                               const float* __restrict__ PS,
                                               const float* __restrict__ S,
                                               int* __restrict__ cnt,
                                               float* __restrict__ acc,
                                               float* __restrict__ out) {
    __shared__ float Ss[NCLS * KD];
    __shared__ int cs[NCLS];
    int t = threadIdx.x;
    for (int i = t; i < NCLS * KD; i += 256) Ss[i] = S[i];
    if (t < NCLS) cs[t] = cnt[t];
    __syncthreads();

    int g = t >> 2, q = t & 3;            // 4 lanes per row
    int row = blockIdx.x * 64 + g;
    int c = tgt[row];
    float dot = 0.f;
#pragma unroll
    for (int i = 0; i < 8; ++i) {
        float4 f = *(const float4*)(F + (size_t)row * KD + i * 16 + q * 4);
        float4 s = *(const float4*)(Ss + c * KD + i * 16 + q * 4);
        dot += f.x * s.x + f.y * s.y + f.z * s.z + f.w * s.w;
    }
    dot += __shfl_xor(dot, 1, 4);
    dot += __shfl_xor(dot, 2, 4);

    float mlp = 0.f;
    if (q == 0) {
        float M = diag10[row];
        float pp = 10.f * dot - M;            // sum over positives of logits
        float T = PS[row];                    // surviving shifted exp mass
        float np = (float)(cs[c] - 1);
        mlp = (np < 0.5f) ? 0.f : (pp - np * (M + __logf(T + 1e-20f))) / np;
    }
#pragma unroll
    for (int off = 32; off >= 1; off >>= 1) mlp += __shfl_xor(mlp, off);
    __shared__ float wsum[4];
    int lane = t & 63, w = t >> 6;
    if (lane == 0) wsum[w] = mlp;
    __syncthreads();
    if (t == 0) {
        atomicAdd(acc, (wsum[0] + wsum[1]) + (wsum[2] + wsum[3]));
        __threadfence();
        int old = atomicAdd(&cnt[12], 1);   // ticket
        if (old == (int)gridDim.x - 1) {
            float tot = atomicAdd(acc, 0.0f);   // coherent read of total
            double sp = 0.0, sn = 0.0;
            for (int cc = 0; cc < NCLS; ++cc) {
                double n = (double)cs[cc];
                sp += n * (n - 1.0);
                sn += n * ((double)N - n);
            }
            out[0] = (float)(-(0.1 / 0.07) * ((double)tot / (double)N));
            out[1] = (float)(sp / (double)N);
            out[2] = (float)(sn / (double)N);
        }
    }
}

extern "C" void kernel_launch(void* const* d_in, const int* in_sizes, int n_in,
                              void* d_out, int out_size, void* d_ws, size_t ws_size,
                              hipStream_t stream) {
    const float* F = (const float*)d_in[0];
    const int* tgt = (const int*)d_in[1];
    float* out = (float*)d_out;
    char* ws = (char*)d_ws;

    int* cnt = (int*)(ws);                       // 64 B (ticket at cnt[12])
    float* acc = (float*)(ws + 64);              // 4 B
    float* S = (float*)(ws + 128);               // 5120 B -> ends 5248
    float* PS = (float*)(ws + 8192);             // 32 KiB (zeroed by k_conv)
    int* Dpart = (int*)(ws + 49152);             // 2 KiB (per-16-row diag mins, plain stores)
    float* diag10 = (float*)(ws + 65536);        // 32 KiB
    int* Q = (int*)(ws + (1u << 20));            // 1 MiB (i8 frags of 30*F)

    hipMemsetAsync(ws, 0, 8192, stream);         // cnt + acc + S
    k_conv<<<640, 256, 0, stream>>>(F, tgt, diag10, Q, S, cnt, PS, Dpart);
    k_pair<<<dim3(128, 4), 256, 0, stream>>>((const unsigned char*)Q, diag10, PS, Dpart);
    k_final<<<N / 64, 256, 0, stream>>>(F, tgt, diag10, PS, S, cnt, acc, out);
}